// Round 3
// baseline (248.992 us; speedup 1.0000x reference)
//
#include <hip/hip_runtime.h>
#include <hip/hip_bf16.h>

#define TT      5
#define NHEADS  6
#define DIMC    192
#define SHIFT_  4
#define HDIM_   32
#define NTOK    320
#define NWIN    64
#define BATCH   2
#define LOG2E   1.44269504088896f
#define SCALE_LOG2E (0.17677669529663687f * 1.44269504088896f)
#define NEGMASK (-100.0f * 1.44269504088896f)

typedef short short8v __attribute__((ext_vector_type(8)));
typedef float floatx4 __attribute__((ext_vector_type(4)));
union FragU { uint4 u; short8v s; };

static __device__ __forceinline__ float bf16lo(unsigned u) {
    union { unsigned i; float f; } x; x.i = u << 16; return x.f;
}
static __device__ __forceinline__ float bf16hi(unsigned u) {
    union { unsigned i; float f; } x; x.i = u & 0xffff0000u; return x.f;
}
static __device__ __forceinline__ unsigned short bf16b(float f) {
    __hip_bfloat16 h = __float2bfloat16(f);
    unsigned short u; __builtin_memcpy(&u, &h, 2); return u;
}
static __device__ __forceinline__ unsigned pk2(float a, float b) {
    return (unsigned)bf16b(a) | ((unsigned)bf16b(b) << 16);
}
// fast half-up bf16 pair pack (P-matrix only: e >= 0, never NaN; <=1ulp bias)
static __device__ __forceinline__ unsigned pk2h(float a, float b) {
    unsigned ua = __float_as_uint(a), ub = __float_as_uint(b);
    return ((ua + 0x8000u) >> 16) | ((ub + 0x8000u) & 0xffff0000u);
}

// Runtime dtype sniffer (bf16-pair vs f32 data) — wave-uniform, deterministic.
static __device__ __forceinline__ bool detect_bf16(const unsigned* q) {
    uint4 w = ((const uint4*)q)[threadIdx.x & 63];
    int cnt = 0;
    unsigned e;
    e = (w.x >> 7) & 0xffu; cnt += (e >= 100u && e <= 135u);
    e = (w.y >> 7) & 0xffu; cnt += (e >= 100u && e <= 135u);
    e = (w.z >> 7) & 0xffu; cnt += (e >= 100u && e <= 135u);
    e = (w.w >> 7) & 0xffu; cnt += (e >= 100u && e <= 135u);
    unsigned long long m = __ballot(cnt >= 2);
    return __popcll(m) >= 32;
}

// ---------------------------------------------------------------------------
// Attention: 1 block per (window b_, head h). 5 waves x 64 queries.
// LDS 46.3 KB -> 3 blocks/CU (15 waves/CU). Plain launch_bounds(320) — the
// min-waves variant is re-tested as a LONE delta in a later round.
//
// KEY-SLOT PERMUTATION: K rows are staged so that within each 32-key block,
// logical key l = q4*8 + kt*4 + reg sits at MFMA tile slot kt*16 + q4*4 + reg.
// After the two S^T = K*Q^T MFMAs, lane (l15,quad) holds exactly keys
// quad*8 + kt*4 + reg — the PV operand k-order — so P packs in-register.
//
//  * cooperative coalesced staging: 8-lane groups cover one token's 128-B
//    K/V slice (dwordx4/lane) -> 8 fully-used lines per wave instr (was 64).
//  * PV operand swap: oacc = mfma(V^T_frag, P_frag) = (P.V)^T[dim][query];
//    lane owns 4 consecutive dims of one query -> dwordx2 stores (8/lane
//    instead of 32 b16) and the row-sum it needs is its own post-butterfly
//    rs value -> sRS LDS buffer deleted.
//  * bf16 packing via proven pk2/pk2h helpers (R0); no inline-asm cvt_pk.
// ---------------------------------------------------------------------------
__global__ __launch_bounds__(NTOK) void attn_mfma(
    const void* __restrict__ qkv_raw,
    const void* __restrict__ bias_raw,
    __hip_bfloat16* __restrict__ win_out)          // ws: [B_][320][192]
{
    const bool isbf = detect_bf16((const unsigned*)qkv_raw);
    const int b_  = blockIdx.x;       // 0..127
    const int h   = blockIdx.y;       // 0..5
    const int bb  = b_ >> 6;
    const int wdx = b_ & 63;
    const int wi  = wdx >> 3, wj = wdx & 7;
    const int tid = threadIdx.x;
    const int w    = tid >> 6;        // wave 0..4
    const int lane = tid & 63;
    const int l15  = lane & 15;
    const int quad = lane >> 4;       // 0..3
    const int g    = lane >> 3;       // segment group 0..7
    const int li   = lane & 7;        // lane within segment

    __shared__ unsigned short sK[320 * 40];    // K rows bf16 (slot-permuted), stride 40
    __shared__ unsigned short sVT[32 * 328];   // V^T [dim][token]
    __shared__ float sBias[192];               // head's bias column * LOG2E

    if (tid < 192)
        sBias[tid] = (isbf ? __bfloat162float(((const __hip_bfloat16*)bias_raw)[tid * NHEADS + h])
                           : ((const float*)bias_raw)[tid * NHEADS + h]) * LOG2E;

    // ---- staging: 8-lane groups cooperatively load one token's 128-B K/V
    //      slice (fully coalesced, each segment = one aligned 128-B line) ----
    {
        const int btok = w * 64;
        if (!isbf) {
            const float* q32 = (const float*)qkv_raw;
            #pragma unroll
            for (int r = 0; r < 8; r++) {                    // K rounds
                const int token = btok + r * 8 + g;
                const int t = token >> 6, s = token & 63;
                const int gh = (wi * 8 + (s >> 3) + SHIFT_) & 63;
                const int gw = (wj * 8 + (s & 7) + SHIFT_) & 63;
                const long grow = (long)bb * (TT * 64 * 64) + t * 4096 + gh * 64 + gw;
                const float4 kv = *(const float4*)(q32 + grow * (3 * DIMC) + DIMC + h * HDIM_ + li * 4);
                const int l32 = token & 31;
                const int slot = (token & ~31) + ((l32 & 4) << 2) + ((l32 >> 3) << 2) + (l32 & 3);
                *(uint2*)&sK[slot * 40 + li * 4] = make_uint2(pk2(kv.x, kv.y), pk2(kv.z, kv.w));
            }
            #pragma unroll
            for (int r = 0; r < 8; r++) {                    // V rounds
                const int token = btok + r * 8 + g;
                const int t = token >> 6, s = token & 63;
                const int gh = (wi * 8 + (s >> 3) + SHIFT_) & 63;
                const int gw = (wj * 8 + (s & 7) + SHIFT_) & 63;
                const long grow = (long)bb * (TT * 64 * 64) + t * 4096 + gh * 64 + gw;
                const float4 vv = *(const float4*)(q32 + grow * (3 * DIMC) + 2 * DIMC + h * HDIM_ + li * 4);
                const int d0 = li * 4;
                sVT[(d0 + 0) * 328 + token] = bf16b(vv.x);
                sVT[(d0 + 1) * 328 + token] = bf16b(vv.y);
                sVT[(d0 + 2) * 328 + token] = bf16b(vv.z);
                sVT[(d0 + 3) * 328 + token] = bf16b(vv.w);
            }
        } else {
            const unsigned short* q16 = (const unsigned short*)qkv_raw;
            #pragma unroll
            for (int r = 0; r < 8; r++) {                    // K rounds
                const int token = btok + r * 8 + g;
                const int t = token >> 6, s = token & 63;
                const int gh = (wi * 8 + (s >> 3) + SHIFT_) & 63;
                const int gw = (wj * 8 + (s & 7) + SHIFT_) & 63;
                const long grow = (long)bb * (TT * 64 * 64) + t * 4096 + gh * 64 + gw;
                const uint2 kv = *(const uint2*)(q16 + grow * (3 * DIMC) + DIMC + h * HDIM_ + li * 4);
                const int l32 = token & 31;
                const int slot = (token & ~31) + ((l32 & 4) << 2) + ((l32 >> 3) << 2) + (l32 & 3);
                *(uint2*)&sK[slot * 40 + li * 4] = kv;
            }
            #pragma unroll
            for (int r = 0; r < 8; r++) {                    // V rounds
                const int token = btok + r * 8 + g;
                const int t = token >> 6, s = token & 63;
                const int gh = (wi * 8 + (s >> 3) + SHIFT_) & 63;
                const int gw = (wj * 8 + (s & 7) + SHIFT_) & 63;
                const long grow = (long)bb * (TT * 64 * 64) + t * 4096 + gh * 64 + gw;
                const uint2 vv = *(const uint2*)(q16 + grow * (3 * DIMC) + 2 * DIMC + h * HDIM_ + li * 4);
                const int d0 = li * 4;
                sVT[(d0 + 0) * 328 + token] = (unsigned short)(vv.x & 0xffffu);
                sVT[(d0 + 1) * 328 + token] = (unsigned short)(vv.x >> 16);
                sVT[(d0 + 2) * 328 + token] = (unsigned short)(vv.y & 0xffffu);
                sVT[(d0 + 3) * 328 + token] = (unsigned short)(vv.y >> 16);
            }
        }
    }

    // ---- per-lane Q fragments (B-operand: n=query=l15, k=dim=quad*8+j) ----
    FragU qf[4];
    int cn_q[4], labq[4];
    #pragma unroll
    for (int jq = 0; jq < 4; jq++) {
        const int qtok = w * 64 + jq * 16 + l15;
        const int t = qtok >> 6, s = qtok & 63, hl = s >> 3, wl = s & 7;
        cn_q[jq] = t * 15 + hl + wl;
        const int hh = wi * 8 + hl, ww = wj * 8 + wl;
        labq[jq] = ((hh < 56) ? 0 : ((hh < 60) ? 1 : 2)) * 3 +
                   ((ww < 56) ? 0 : ((ww < 60) ? 1 : 2));
        const int gh = (wi * 8 + hl + SHIFT_) & 63;
        const int gw = (wj * 8 + wl + SHIFT_) & 63;
        const long grow = (long)bb * (TT * 64 * 64) + t * 4096 + gh * 64 + gw;
        if (!isbf) {
            const float* qp = (const float*)qkv_raw + grow * (3 * DIMC) + h * HDIM_ + quad * 8;
            qf[jq].u = make_uint4(
                pk2(qp[0]*SCALE_LOG2E, qp[1]*SCALE_LOG2E), pk2(qp[2]*SCALE_LOG2E, qp[3]*SCALE_LOG2E),
                pk2(qp[4]*SCALE_LOG2E, qp[5]*SCALE_LOG2E), pk2(qp[6]*SCALE_LOG2E, qp[7]*SCALE_LOG2E));
        } else {
            const uint4 uu = *(const uint4*)((const __hip_bfloat16*)qkv_raw + grow * (3 * DIMC) + h * HDIM_ + quad * 8);
            qf[jq].u = make_uint4(
                pk2(bf16lo(uu.x)*SCALE_LOG2E, bf16hi(uu.x)*SCALE_LOG2E),
                pk2(bf16lo(uu.y)*SCALE_LOG2E, bf16hi(uu.y)*SCALE_LOG2E),
                pk2(bf16lo(uu.z)*SCALE_LOG2E, bf16hi(uu.z)*SCALE_LOG2E),
                pk2(bf16lo(uu.w)*SCALE_LOG2E, bf16hi(uu.w)*SCALE_LOG2E));
        }
    }
    __syncthreads();

    const floatx4 z4 = {0.f, 0.f, 0.f, 0.f};
    floatx4 oacc[4][2];                      // (P.V)^T: [query-tile][dim-16-tile]
    #pragma unroll
    for (int i = 0; i < 4; i++) { oacc[i][0] = z4; oacc[i][1] = z4; }
    float rs[4] = {0.f, 0.f, 0.f, 0.f};

    for (int kb = 0; kb < 10; kb++) {
        FragU kf0, kf1, vf0, vf1;
        kf0.u = *(const uint4*)&sK[(kb * 32 + l15) * 40 + quad * 8];
        kf1.u = *(const uint4*)&sK[(kb * 32 + 16 + l15) * 40 + quad * 8];
        vf0.u = *(const uint4*)&sVT[l15 * 328 + kb * 32 + quad * 8];
        vf1.u = *(const uint4*)&sVT[(16 + l15) * 328 + kb * 32 + quad * 8];

        floatx4 sv0[4], sv1[4];
        #pragma unroll
        for (int jq = 0; jq < 4; jq++)
            sv0[jq] = __builtin_amdgcn_mfma_f32_16x16x32_bf16(kf0.s, qf[jq].s, z4, 0, 0, 0);
        #pragma unroll
        for (int jq = 0; jq < 4; jq++)
            sv1[jq] = __builtin_amdgcn_mfma_f32_16x16x32_bf16(kf1.s, qf[jq].s, z4, 0, 0, 0);

        // logical key for (kt, reg) at this lane: kb*32 + quad*8 + kt*4 + reg
        const int Ck   = (7 - (kb >> 1)) * 15 + 7;
        const int sh   = (kb & 1) * 4 + quad;
        const int rhk  = (wi == 7) ? ((sh < 4) ? 1 : 2) : 0;
        const int lab0 = rhk * 3 + ((wj == 7) ? 1 : 0);   // kt0: sw=reg<4
        const int lab1 = rhk * 3 + ((wj == 7) ? 2 : 0);   // kt1: sw=4+reg
        const int cb   = Ck - sh;

        #pragma unroll
        for (int jq = 0; jq < 4; jq++) {
            const int bidx = cn_q[jq] + cb;
            const float m0 = (lab0 != labq[jq]) ? NEGMASK : 0.f;
            const float m1 = (lab1 != labq[jq]) ? NEGMASK : 0.f;
            float e0[4], e1[4];
            #pragma unroll
            for (int reg = 0; reg < 4; reg++)
                e0[reg] = exp2f(sv0[jq][reg] + sBias[bidx - reg] + m0);
            #pragma unroll
            for (int reg = 0; reg < 4; reg++)
                e1[reg] = exp2f(sv1[jq][reg] + sBias[bidx - 4 - reg] + m1);
            rs[jq] += ((e0[0] + e0[1]) + (e0[2] + e0[3]))
                    + ((e1[0] + e1[1]) + (e1[2] + e1[3]));
            FragU pf;
            pf.u.x = pk2h(e0[0], e0[1]); pf.u.y = pk2h(e0[2], e0[3]);
            pf.u.z = pk2h(e1[0], e1[1]); pf.u.w = pk2h(e1[2], e1[3]);
            // swapped operands: D = V^T . P^T = (P.V)^T  ->  D[dim][query]
            oacc[jq][0] = __builtin_amdgcn_mfma_f32_16x16x32_bf16(vf0.s, pf.s, oacc[jq][0], 0, 0, 0);
            oacc[jq][1] = __builtin_amdgcn_mfma_f32_16x16x32_bf16(vf1.s, pf.s, oacc[jq][1], 0, 0, 0);
        }
    }

    // ---- epilogue: rs butterfly leaves every lane with the row-sum of its
    //      own l15-query; lane owns 4 consecutive dims -> dwordx2 stores ----
    unsigned short* wp = (unsigned short*)win_out;
    #pragma unroll
    for (int jq = 0; jq < 4; jq++) {
        float r = rs[jq];
        r += __shfl_xor(r, 16);
        r += __shfl_xor(r, 32);
        const float inv = 1.0f / r;
        const long ob = ((long)b_ * NTOK + (w * 64 + jq * 16 + l15)) * DIMC + h * HDIM_ + quad * 4;
        #pragma unroll
        for (int nt = 0; nt < 2; nt++) {
            const floatx4 o = oacc[jq][nt];
            *(uint2*)&wp[ob + nt * 16] =
                make_uint2(pk2(o[0] * inv, o[1] * inv), pk2(o[2] * inv, o[3] * inv));
        }
    }
}

// ---------------------------------------------------------------------------
// prep_w: one-time W -> bf16 and bias -> f32 into workspace.
// ---------------------------------------------------------------------------
__global__ __launch_bounds__(256) void prep_w(
    const void* __restrict__ w_raw, const void* __restrict__ b_raw,
    const unsigned* __restrict__ sniff,
    unsigned short* __restrict__ wbf, float* __restrict__ bf32)
{
    const bool isbf = detect_bf16(sniff);
    const int g = blockIdx.x * 256 + threadIdx.x;   // grid sized exactly 36864
    if (!isbf) wbf[g] = bf16b(((const float*)w_raw)[g]);
    else       wbf[g] = ((const unsigned short*)w_raw)[g];
    if (blockIdx.x == 0 && threadIdx.x < 192) {
        bf32[threadIdx.x] = isbf
            ? __bfloat162float(((const __hip_bfloat16*)b_raw)[threadIdx.x])
            : ((const float*)b_raw)[threadIdx.x];
    }
}

// ---------------------------------------------------------------------------
// Projection GEMM, zero LDS: M=64 tokens/block (4 waves x 16), N=192, K=192.
// Swapped operands: acc = mfma(W_frag, x_frag) = out^T[outdim][token] -> each
// lane owns 4 consecutive out-dims of ONE token => vectorized stores
// (dwordx4 f32 / dwordx2 bf16; was 48 scalar f32 stores) and a single
// row-decode per lane (was 4).
// ---------------------------------------------------------------------------
__global__ __launch_bounds__(256) void proj_mfma(
    const __hip_bfloat16* __restrict__ win,       // ws: [B_][320][192]
    const unsigned short* __restrict__ wbf,       // ws: [192][192] bf16
    const float* __restrict__ bf32,               // ws: [192] f32
    const unsigned* __restrict__ sniff,
    void* __restrict__ out_raw)                   // [B][T*64*64][192]
{
    const bool isbf = detect_bf16(sniff);
    const int tid  = threadIdx.x;
    const int w    = tid >> 6;
    const int lane = tid & 63;
    const int l15  = lane & 15;
    const int quad = lane >> 4;
    const int tok0 = blockIdx.x * 64 + w * 16;

    const floatx4 z4 = {0.f, 0.f, 0.f, 0.f};
    floatx4 acc[12];
    #pragma unroll
    for (int nt = 0; nt < 12; nt++) acc[nt] = z4;

    #pragma unroll
    for (int ks = 0; ks < 6; ks++) {
        FragU xf;
        xf.u = *(const uint4*)((const unsigned short*)win + ((long)tok0 + l15) * DIMC + ks * 32 + quad * 8);
        #pragma unroll
        for (int nt = 0; nt < 12; nt++) {
            FragU wf;
            wf.u = *(const uint4*)(wbf + (nt * 16 + l15) * DIMC + ks * 32 + quad * 8);
            // A = W rows (outdim), B = x^T (token cols) -> D[outdim][token]
            acc[nt] = __builtin_amdgcn_mfma_f32_16x16x32_bf16(wf.s, xf.s, acc[nt], 0, 0, 0);
        }
    }

    // one output-row decode per lane: token = tok0 + l15
    const int token = tok0 + l15;
    const int bw = token / NTOK;
    const int nn = token - bw * NTOK;
    const int bb = bw >> 6, wdx = bw & 63, wi2 = wdx >> 3, wj2 = wdx & 7;
    const int t = nn >> 6, s2 = nn & 63, hl = s2 >> 3, wl = s2 & 7;
    const int gh = (wi2 * 8 + hl + SHIFT_) & 63;
    const int gw = (wj2 * 8 + wl + SHIFT_) & 63;
    const long rowoff = ((long)bb * (TT * 64 * 64) + t * 4096 + gh * 64 + gw) * DIMC;

    #pragma unroll
    for (int nt = 0; nt < 12; nt++) {
        const float4 bv = *(const float4*)&bf32[nt * 16 + quad * 4];
        const float o0 = acc[nt][0] + bv.x, o1 = acc[nt][1] + bv.y;
        const float o2 = acc[nt][2] + bv.z, o3 = acc[nt][3] + bv.w;
        const long off = rowoff + nt * 16 + quad * 4;
        if (!isbf) {
            *(float4*)((float*)out_raw + off) = make_float4(o0, o1, o2, o3);
        } else {
            *(uint2*)((unsigned short*)out_raw + off) = make_uint2(pk2(o0, o1), pk2(o2, o3));
        }
    }
}

extern "C" void kernel_launch(void* const* d_in, const int* in_sizes, int n_in,
                              void* d_out, int out_size, void* d_ws, size_t ws_size,
                              hipStream_t stream)
{
    (void)in_sizes; (void)n_in; (void)out_size; (void)ws_size;
    const void* qkv        = d_in[0];
    const void* bias_table = d_in[1];
    const void* proj_w     = d_in[2];
    const void* proj_b     = d_in[3];

    __hip_bfloat16* win = (__hip_bfloat16*)d_ws;                         // 15,728,640 B
    unsigned short* wbf = (unsigned short*)((char*)d_ws + 15728640);     //     73,728 B
    float*          bfb = (float*)((char*)d_ws + 15802368);              //        768 B

    prep_w<<<dim3(144), 256, 0, stream>>>(proj_w, proj_b, (const unsigned*)qkv, wbf, bfb);
    attn_mfma<<<dim3(BATCH * NWIN, NHEADS), NTOK, 0, stream>>>(qkv, bias_table, win);
    proj_mfma<<<dim3(BATCH * NWIN * NTOK / 64), 256, 0, stream>>>(
        win, wbf, bfb, (const unsigned*)qkv, d_out);
}

// Round 5
// 240.099 us; speedup vs baseline: 1.0370x; 1.0370x over previous
//
#include <hip/hip_runtime.h>
#include <hip/hip_bf16.h>

#define TT      5
#define NHEADS  6
#define DIMC    192
#define SHIFT_  4
#define HDIM_   32
#define NTOK    320
#define NWIN    64
#define BATCH   2
#define ATHREADS 640
#define LOG2E   1.44269504088896f
#define SCALE_LOG2E (0.17677669529663687f * 1.44269504088896f)
#define NEGMASK (-100.0f * 1.44269504088896f)

typedef short short8v __attribute__((ext_vector_type(8)));
typedef float floatx4 __attribute__((ext_vector_type(4)));
union FragU { uint4 u; short8v s; };

static __device__ __forceinline__ float bf16lo(unsigned u) {
    union { unsigned i; float f; } x; x.i = u << 16; return x.f;
}
static __device__ __forceinline__ float bf16hi(unsigned u) {
    union { unsigned i; float f; } x; x.i = u & 0xffff0000u; return x.f;
}
static __device__ __forceinline__ unsigned short bf16b(float f) {
    __hip_bfloat16 h = __float2bfloat16(f);
    unsigned short u; __builtin_memcpy(&u, &h, 2); return u;
}
static __device__ __forceinline__ unsigned pk2(float a, float b) {
    return (unsigned)bf16b(a) | ((unsigned)bf16b(b) << 16);
}
// fast half-up bf16 pair pack (P-matrix only: e >= 0, never NaN; <=1ulp bias)
static __device__ __forceinline__ unsigned pk2h(float a, float b) {
    unsigned ua = __float_as_uint(a), ub = __float_as_uint(b);
    return ((ua + 0x8000u) >> 16) | ((ub + 0x8000u) & 0xffff0000u);
}

// Runtime dtype sniffer (bf16-pair vs f32 data) — wave-uniform, deterministic.
static __device__ __forceinline__ bool detect_bf16(const unsigned* q) {
    uint4 w = ((const uint4*)q)[threadIdx.x & 63];
    int cnt = 0;
    unsigned e;
    e = (w.x >> 7) & 0xffu; cnt += (e >= 100u && e <= 135u);
    e = (w.y >> 7) & 0xffu; cnt += (e >= 100u && e <= 135u);
    e = (w.z >> 7) & 0xffu; cnt += (e >= 100u && e <= 135u);
    e = (w.w >> 7) & 0xffu; cnt += (e >= 100u && e <= 135u);
    unsigned long long m = __ballot(cnt >= 2);
    return __popcll(m) >= 32;
}

// ---------------------------------------------------------------------------
// Attention: 1 block per (window b_, head h). R4/R5: 10 waves x 32 queries
// (was 5 x 64). Rationale: R3 counters showed all pipes <35% busy and
// OccupancyPercent ~13% (~1 wave/SIMD progressing) -> latency-bound. Halving
// per-wave critical path (2 query-tiles instead of 4) and doubling wave
// parallelism attacks exposed-stall time directly. LDS unchanged (47.4 KB,
// 3 blocks/CU by LDS; 1920 threads <= 2048/CU).
//
// KEY-SLOT PERMUTATION: K rows are staged so that within each 32-key block,
// logical key l = q4*8 + kt*4 + reg sits at MFMA tile slot kt*16 + q4*4 + reg.
// After the two S^T = K*Q^T MFMAs, lane (l15,quad) holds exactly keys
// quad*8 + kt*4 + reg — the PV operand k-order — so P packs in-register.
//
//  * cooperative coalesced staging: 8-lane groups cover one token's 128-B
//    K/V slice (dwordx4/lane); each wave stages its own 32 tokens (4 rounds).
//  * PV operand swap: oacc = mfma(V^T_frag, P_frag) = (P.V)^T[dim][query];
//    lane owns 4 consecutive dims of one query -> dwordx2 stores, and the
//    row-sum it needs is its own post-butterfly rs value.
// ---------------------------------------------------------------------------
__global__ __launch_bounds__(ATHREADS) void attn_mfma(
    const void* __restrict__ qkv_raw,
    const void* __restrict__ bias_raw,
    __hip_bfloat16* __restrict__ win_out)          // ws: [B_][320][192]
{
    const bool isbf = detect_bf16((const unsigned*)qkv_raw);
    const int b_  = blockIdx.x;       // 0..127
    const int h   = blockIdx.y;       // 0..5
    const int bb  = b_ >> 6;
    const int wdx = b_ & 63;
    const int wi  = wdx >> 3, wj = wdx & 7;
    const int tid = threadIdx.x;
    const int w    = tid >> 6;        // wave 0..9
    const int lane = tid & 63;
    const int l15  = lane & 15;
    const int quad = lane >> 4;       // 0..3
    const int g    = lane >> 3;       // segment group 0..7
    const int li   = lane & 7;        // lane within segment

    __shared__ unsigned short sK[320 * 40];    // K rows bf16 (slot-permuted), stride 40
    __shared__ unsigned short sVT[32 * 328];   // V^T [dim][token]
    __shared__ float sBias[192];               // head's bias column * LOG2E

    if (tid < 192)
        sBias[tid] = (isbf ? __bfloat162float(((const __hip_bfloat16*)bias_raw)[tid * NHEADS + h])
                           : ((const float*)bias_raw)[tid * NHEADS + h]) * LOG2E;

    // ---- staging: 8-lane groups cooperatively load one token's 128-B K/V
    //      slice (fully coalesced); each wave covers its own 32 tokens ----
    {
        const int btok = w * 32;
        if (!isbf) {
            const float* q32 = (const float*)qkv_raw;
            #pragma unroll
            for (int r = 0; r < 4; r++) {                    // K rounds
                const int token = btok + r * 8 + g;
                const int t = token >> 6, s = token & 63;
                const int gh = (wi * 8 + (s >> 3) + SHIFT_) & 63;
                const int gw = (wj * 8 + (s & 7) + SHIFT_) & 63;
                const long grow = (long)bb * (TT * 64 * 64) + t * 4096 + gh * 64 + gw;
                const float4 kv = *(const float4*)(q32 + grow * (3 * DIMC) + DIMC + h * HDIM_ + li * 4);
                const int l32 = token & 31;
                const int slot = (token & ~31) + ((l32 & 4) << 2) + ((l32 >> 3) << 2) + (l32 & 3);
                *(uint2*)&sK[slot * 40 + li * 4] = make_uint2(pk2(kv.x, kv.y), pk2(kv.z, kv.w));
            }
            #pragma unroll
            for (int r = 0; r < 4; r++) {                    // V rounds
                const int token = btok + r * 8 + g;
                const int t = token >> 6, s = token & 63;
                const int gh = (wi * 8 + (s >> 3) + SHIFT_) & 63;
                const int gw = (wj * 8 + (s & 7) + SHIFT_) & 63;
                const long grow = (long)bb * (TT * 64 * 64) + t * 4096 + gh * 64 + gw;
                const float4 vv = *(const float4*)(q32 + grow * (3 * DIMC) + 2 * DIMC + h * HDIM_ + li * 4);
                const int d0 = li * 4;
                sVT[(d0 + 0) * 328 + token] = bf16b(vv.x);
                sVT[(d0 + 1) * 328 + token] = bf16b(vv.y);
                sVT[(d0 + 2) * 328 + token] = bf16b(vv.z);
                sVT[(d0 + 3) * 328 + token] = bf16b(vv.w);
            }
        } else {
            const unsigned short* q16 = (const unsigned short*)qkv_raw;
            #pragma unroll
            for (int r = 0; r < 4; r++) {                    // K rounds
                const int token = btok + r * 8 + g;
                const int t = token >> 6, s = token & 63;
                const int gh = (wi * 8 + (s >> 3) + SHIFT_) & 63;
                const int gw = (wj * 8 + (s & 7) + SHIFT_) & 63;
                const long grow = (long)bb * (TT * 64 * 64) + t * 4096 + gh * 64 + gw;
                const uint2 kv = *(const uint2*)(q16 + grow * (3 * DIMC) + DIMC + h * HDIM_ + li * 4);
                const int l32 = token & 31;
                const int slot = (token & ~31) + ((l32 & 4) << 2) + ((l32 >> 3) << 2) + (l32 & 3);
                *(uint2*)&sK[slot * 40 + li * 4] = kv;
            }
            #pragma unroll
            for (int r = 0; r < 4; r++) {                    // V rounds
                const int token = btok + r * 8 + g;
                const int t = token >> 6, s = token & 63;
                const int gh = (wi * 8 + (s >> 3) + SHIFT_) & 63;
                const int gw = (wj * 8 + (s & 7) + SHIFT_) & 63;
                const long grow = (long)bb * (TT * 64 * 64) + t * 4096 + gh * 64 + gw;
                const uint2 vv = *(const uint2*)(q16 + grow * (3 * DIMC) + 2 * DIMC + h * HDIM_ + li * 4);
                const int d0 = li * 4;
                sVT[(d0 + 0) * 328 + token] = (unsigned short)(vv.x & 0xffffu);
                sVT[(d0 + 1) * 328 + token] = (unsigned short)(vv.x >> 16);
                sVT[(d0 + 2) * 328 + token] = (unsigned short)(vv.y & 0xffffu);
                sVT[(d0 + 3) * 328 + token] = (unsigned short)(vv.y >> 16);
            }
        }
    }

    // ---- per-lane Q fragments (B-operand: n=query=l15, k=dim=quad*8+j) ----
    FragU qf[2];
    int cn_q[2], labq[2];
    #pragma unroll
    for (int jq = 0; jq < 2; jq++) {
        const int qtok = w * 32 + jq * 16 + l15;
        const int t = qtok >> 6, s = qtok & 63, hl = s >> 3, wl = s & 7;
        cn_q[jq] = t * 15 + hl + wl;
        const int hh = wi * 8 + hl, ww = wj * 8 + wl;
        labq[jq] = ((hh < 56) ? 0 : ((hh < 60) ? 1 : 2)) * 3 +
                   ((ww < 56) ? 0 : ((ww < 60) ? 1 : 2));
        const int gh = (wi * 8 + hl + SHIFT_) & 63;
        const int gw = (wj * 8 + wl + SHIFT_) & 63;
        const long grow = (long)bb * (TT * 64 * 64) + t * 4096 + gh * 64 + gw;
        if (!isbf) {
            const float* qp = (const float*)qkv_raw + grow * (3 * DIMC) + h * HDIM_ + quad * 8;
            qf[jq].u = make_uint4(
                pk2(qp[0]*SCALE_LOG2E, qp[1]*SCALE_LOG2E), pk2(qp[2]*SCALE_LOG2E, qp[3]*SCALE_LOG2E),
                pk2(qp[4]*SCALE_LOG2E, qp[5]*SCALE_LOG2E), pk2(qp[6]*SCALE_LOG2E, qp[7]*SCALE_LOG2E));
        } else {
            const uint4 uu = *(const uint4*)((const __hip_bfloat16*)qkv_raw + grow * (3 * DIMC) + h * HDIM_ + quad * 8);
            qf[jq].u = make_uint4(
                pk2(bf16lo(uu.x)*SCALE_LOG2E, bf16hi(uu.x)*SCALE_LOG2E),
                pk2(bf16lo(uu.y)*SCALE_LOG2E, bf16hi(uu.y)*SCALE_LOG2E),
                pk2(bf16lo(uu.z)*SCALE_LOG2E, bf16hi(uu.z)*SCALE_LOG2E),
                pk2(bf16lo(uu.w)*SCALE_LOG2E, bf16hi(uu.w)*SCALE_LOG2E));
        }
    }
    __syncthreads();

    const floatx4 z4 = {0.f, 0.f, 0.f, 0.f};
    floatx4 oacc[2][2];                      // (P.V)^T: [query-tile][dim-16-tile]
    #pragma unroll
    for (int i = 0; i < 2; i++) { oacc[i][0] = z4; oacc[i][1] = z4; }
    float rs[2] = {0.f, 0.f};

    for (int kb = 0; kb < 10; kb++) {
        FragU kf0, kf1, vf0, vf1;
        kf0.u = *(const uint4*)&sK[(kb * 32 + l15) * 40 + quad * 8];
        kf1.u = *(const uint4*)&sK[(kb * 32 + 16 + l15) * 40 + quad * 8];
        vf0.u = *(const uint4*)&sVT[l15 * 328 + kb * 32 + quad * 8];
        vf1.u = *(const uint4*)&sVT[(16 + l15) * 328 + kb * 32 + quad * 8];

        floatx4 sv0[2], sv1[2];
        #pragma unroll
        for (int jq = 0; jq < 2; jq++)
            sv0[jq] = __builtin_amdgcn_mfma_f32_16x16x32_bf16(kf0.s, qf[jq].s, z4, 0, 0, 0);
        #pragma unroll
        for (int jq = 0; jq < 2; jq++)
            sv1[jq] = __builtin_amdgcn_mfma_f32_16x16x32_bf16(kf1.s, qf[jq].s, z4, 0, 0, 0);

        // logical key for (kt, reg) at this lane: kb*32 + quad*8 + kt*4 + reg
        const int Ck   = (7 - (kb >> 1)) * 15 + 7;
        const int sh   = (kb & 1) * 4 + quad;
        const int rhk  = (wi == 7) ? ((sh < 4) ? 1 : 2) : 0;
        const int lab0 = rhk * 3 + ((wj == 7) ? 1 : 0);   // kt0: sw=reg<4
        const int lab1 = rhk * 3 + ((wj == 7) ? 2 : 0);   // kt1: sw=4+reg
        const int cb   = Ck - sh;

        #pragma unroll
        for (int jq = 0; jq < 2; jq++) {
            const int bidx = cn_q[jq] + cb;
            const float m0 = (lab0 != labq[jq]) ? NEGMASK : 0.f;
            const float m1 = (lab1 != labq[jq]) ? NEGMASK : 0.f;
            float e0[4], e1[4];
            #pragma unroll
            for (int reg = 0; reg < 4; reg++)
                e0[reg] = exp2f(sv0[jq][reg] + sBias[bidx - reg] + m0);
            #pragma unroll
            for (int reg = 0; reg < 4; reg++)
                e1[reg] = exp2f(sv1[jq][reg] + sBias[bidx - 4 - reg] + m1);
            rs[jq] += ((e0[0] + e0[1]) + (e0[2] + e0[3]))
                    + ((e1[0] + e1[1]) + (e1[2] + e1[3]));
            FragU pf;
            pf.u.x = pk2h(e0[0], e0[1]); pf.u.y = pk2h(e0[2], e0[3]);
            pf.u.z = pk2h(e1[0], e1[1]); pf.u.w = pk2h(e1[2], e1[3]);
            // swapped operands: D = V^T . P^T = (P.V)^T  ->  D[dim][query]
            oacc[jq][0] = __builtin_amdgcn_mfma_f32_16x16x32_bf16(vf0.s, pf.s, oacc[jq][0], 0, 0, 0);
            oacc[jq][1] = __builtin_amdgcn_mfma_f32_16x16x32_bf16(vf1.s, pf.s, oacc[jq][1], 0, 0, 0);
        }
    }

    // ---- epilogue: rs butterfly leaves every lane with the row-sum of its
    //      own l15-query; lane owns 4 consecutive dims -> dwordx2 stores ----
    unsigned short* wp = (unsigned short*)win_out;
    #pragma unroll
    for (int jq = 0; jq < 2; jq++) {
        float r = rs[jq];
        r += __shfl_xor(r, 16);
        r += __shfl_xor(r, 32);
        const float inv = 1.0f / r;
        const long ob = ((long)b_ * NTOK + (w * 32 + jq * 16 + l15)) * DIMC + h * HDIM_ + quad * 4;
        #pragma unroll
        for (int nt = 0; nt < 2; nt++) {
            const floatx4 o = oacc[jq][nt];
            *(uint2*)&wp[ob + nt * 16] =
                make_uint2(pk2(o[0] * inv, o[1] * inv), pk2(o[2] * inv, o[3] * inv));
        }
    }
}

// ---------------------------------------------------------------------------
// prep_w: one-time W -> bf16 and bias -> f32 into workspace.
// ---------------------------------------------------------------------------
__global__ __launch_bounds__(256) void prep_w(
    const void* __restrict__ w_raw, const void* __restrict__ b_raw,
    const unsigned* __restrict__ sniff,
    unsigned short* __restrict__ wbf, float* __restrict__ bf32)
{
    const bool isbf = detect_bf16(sniff);
    const int g = blockIdx.x * 256 + threadIdx.x;   // grid sized exactly 36864
    if (!isbf) wbf[g] = bf16b(((const float*)w_raw)[g]);
    else       wbf[g] = ((const unsigned short*)w_raw)[g];
    if (blockIdx.x == 0 && threadIdx.x < 192) {
        bf32[threadIdx.x] = isbf
            ? __bfloat162float(((const __hip_bfloat16*)b_raw)[threadIdx.x])
            : ((const float*)b_raw)[threadIdx.x];
    }
}

// ---------------------------------------------------------------------------
// Projection GEMM, zero LDS: M=64 tokens/block (4 waves x 16), N=192, K=192.
// Swapped operands: acc = mfma(W_frag, x_frag) = out^T[outdim][token] -> each
// lane owns 4 consecutive out-dims of ONE token => vectorized stores
// (dwordx4 f32 / dwordx2 bf16) and a single row-decode per lane.
// ---------------------------------------------------------------------------
__global__ __launch_bounds__(256) void proj_mfma(
    const __hip_bfloat16* __restrict__ win,       // ws: [B_][320][192]
    const unsigned short* __restrict__ wbf,       // ws: [192][192] bf16
    const float* __restrict__ bf32,               // ws: [192] f32
    const unsigned* __restrict__ sniff,
    void* __restrict__ out_raw)                   // [B][T*64*64][192]
{
    const bool isbf = detect_bf16(sniff);
    const int tid  = threadIdx.x;
    const int w    = tid >> 6;
    const int lane = tid & 63;
    const int l15  = lane & 15;
    const int quad = lane >> 4;
    const int tok0 = blockIdx.x * 64 + w * 16;

    const floatx4 z4 = {0.f, 0.f, 0.f, 0.f};
    floatx4 acc[12];
    #pragma unroll
    for (int nt = 0; nt < 12; nt++) acc[nt] = z4;

    #pragma unroll
    for (int ks = 0; ks < 6; ks++) {
        FragU xf;
        xf.u = *(const uint4*)((const unsigned short*)win + ((long)tok0 + l15) * DIMC + ks * 32 + quad * 8);
        #pragma unroll
        for (int nt = 0; nt < 12; nt++) {
            FragU wf;
            wf.u = *(const uint4*)(wbf + (nt * 16 + l15) * DIMC + ks * 32 + quad * 8);
            // A = W rows (outdim), B = x^T (token cols) -> D[outdim][token]
            acc[nt] = __builtin_amdgcn_mfma_f32_16x16x32_bf16(wf.s, xf.s, acc[nt], 0, 0, 0);
        }
    }

    // one output-row decode per lane: token = tok0 + l15
    const int token = tok0 + l15;
    const int bw = token / NTOK;
    const int nn = token - bw * NTOK;
    const int bb = bw >> 6, wdx = bw & 63, wi2 = wdx >> 3, wj2 = wdx & 7;
    const int t = nn >> 6, s2 = nn & 63, hl = s2 >> 3, wl = s2 & 7;
    const int gh = (wi2 * 8 + hl + SHIFT_) & 63;
    const int gw = (wj2 * 8 + wl + SHIFT_) & 63;
    const long rowoff = ((long)bb * (TT * 64 * 64) + t * 4096 + gh * 64 + gw) * DIMC;

    #pragma unroll
    for (int nt = 0; nt < 12; nt++) {
        const float4 bv = *(const float4*)&bf32[nt * 16 + quad * 4];
        const float o0 = acc[nt][0] + bv.x, o1 = acc[nt][1] + bv.y;
        const float o2 = acc[nt][2] + bv.z, o3 = acc[nt][3] + bv.w;
        const long off = rowoff + nt * 16 + quad * 4;
        if (!isbf) {
            *(float4*)((float*)out_raw + off) = make_float4(o0, o1, o2, o3);
        } else {
            *(uint2*)((unsigned short*)out_raw + off) = make_uint2(pk2(o0, o1), pk2(o2, o3));
        }
    }
}

extern "C" void kernel_launch(void* const* d_in, const int* in_sizes, int n_in,
                              void* d_out, int out_size, void* d_ws, size_t ws_size,
                              hipStream_t stream)
{
    (void)in_sizes; (void)n_in; (void)out_size; (void)ws_size;
    const void* qkv        = d_in[0];
    const void* bias_table = d_in[1];
    const void* proj_w     = d_in[2];
    const void* proj_b     = d_in[3];

    __hip_bfloat16* win = (__hip_bfloat16*)d_ws;                         // 15,728,640 B
    unsigned short* wbf = (unsigned short*)((char*)d_ws + 15728640);     //     73,728 B
    float*          bfb = (float*)((char*)d_ws + 15802368);              //        768 B

    prep_w<<<dim3(144), 256, 0, stream>>>(proj_w, proj_b, (const unsigned*)qkv, wbf, bfb);
    attn_mfma<<<dim3(BATCH * NWIN, NHEADS), ATHREADS, 0, stream>>>(qkv, bias_table, win);
    proj_mfma<<<dim3(BATCH * NWIN * NTOK / 64), 256, 0, stream>>>(
        win, wbf, bfb, (const unsigned*)qkv, d_out);
}